// Round 3
// baseline (16856.529 us; speedup 1.0000x reference)
//
#include <hip/hip_runtime.h>

#define Bb 128
#define Tt 512
#define Vv 96
#define Hh 512
#define G4v 2048
#define NBLK 194
#define NTHR 512
#define NSTEP 518
#define OUT_H 6291456
#define OUT_C 6488064

typedef _Float16 f16x4 __attribute__((ext_vector_type(4)));
typedef _Float16 f16x8 __attribute__((ext_vector_type(8)));
typedef float f32x4 __attribute__((ext_vector_type(4)));

struct KP {
  const float *x, *h0, *c0;
  const float *Wih0, *Whh0, *bih0, *bhh0;
  const float *Wih1, *Whh1, *bih1, *bhh1;
  const float *Wih2, *Whh2, *bih2, *bhh2;
  const float *Wfc, *bfc;
  float* out;
  unsigned* bar;     // [0]=gen, [32]=root, [64+g*32]=group counters
  float* fbias;      // [3*2048 + 96]
  _Float16* wimg;    // [194][32768] per-block pre-swizzled LDS images
  float* xg;         // [3][4][Bb][G4v]
  _Float16* xb;      // [Bb][Tt][Vv]
  _Float16* ring;    // [3][4][Bb][Hh]
  float* cbuf;       // [3][Bb][Hh]
};

__device__ __forceinline__ float sigf(float x) { return 1.f / (1.f + __expf(-x)); }

// 2-level grid barrier with spin bailout (deadlock -> terminates, absmax flags it).
__device__ __forceinline__ void gbar(unsigned* bar, unsigned target) {
  __syncthreads();
  if (threadIdx.x == 0) {
    bool last = false;
    const unsigned g = (unsigned)blockIdx.x >> 5;            // 0..6
    const unsigned gcnt = (g == 6u) ? (NBLK - 6 * 32) : 32u;
    unsigned p = __hip_atomic_fetch_add(&bar[64 + g * 32], 1u, __ATOMIC_ACQ_REL, __HIP_MEMORY_SCOPE_AGENT);
    if (p == gcnt - 1u) {
      __hip_atomic_store(&bar[64 + g * 32], 0u, __ATOMIC_RELAXED, __HIP_MEMORY_SCOPE_AGENT);
      unsigned rp = __hip_atomic_fetch_add(&bar[32], 1u, __ATOMIC_ACQ_REL, __HIP_MEMORY_SCOPE_AGENT);
      if (rp == 6u) {
        __hip_atomic_store(&bar[32], 0u, __ATOMIC_RELAXED, __HIP_MEMORY_SCOPE_AGENT);
        __hip_atomic_fetch_add(&bar[0], 1u, __ATOMIC_RELEASE, __HIP_MEMORY_SCOPE_AGENT);
        last = true;
      }
    }
    if (!last) {
      int guard = 0;
      while (__hip_atomic_load(&bar[0], __ATOMIC_ACQUIRE, __HIP_MEMORY_SCOPE_AGENT) < target) {
        if (++guard > 500000) break;   // ~0.1s bailout: deadlock terminates, absmax diagnoses
        __builtin_amdgcn_s_sleep(2);
      }
    }
  }
  __syncthreads();
}

// [128 x NF*16] += A[128 x K] * W^T. 8 waves split M (wave w owns rows w*16..w*16+15).
// W rows in LDS [64][LSTRIDE] f16, optional XOR swizzle baked to match pre-swizzled image.
template <int KSTEPS, int LSTRIDE, bool SWZ, int NF>
__device__ __forceinline__ void gemm1(const _Float16* __restrict__ Abase, int astride,
                                      const _Float16* lds, f32x4 (&acc)[NF]) {
  const int lane = threadIdx.x & 63;
  const int w = threadIdx.x >> 6;
  const int l15 = lane & 15, l4 = lane >> 4;
  const _Float16* ap = Abase + (w * 16 + l15) * astride + l4 * 4;
#pragma unroll 4
  for (int ks = 0; ks < KSTEPS; ++ks) {
    const int kk = ks * 16;
    f16x4 av = *(const f16x4*)(ap + kk);
#pragma unroll
    for (int n = 0; n < NF; ++n) {
      const int r = n * 16 + l15;
      int idx = r * LSTRIDE + kk + l4 * 4;
      if (SWZ) idx ^= (r & 7) << 3;
      f16x4 bv = *(const f16x4*)(lds + idx);
      acc[n] = __builtin_amdgcn_mfma_f32_16x16x16f16(av, bv, acc[n], 0, 0, 0);
    }
  }
}

__global__ __launch_bounds__(256) void prologue_kernel(KP A) {
  const int tid = threadIdx.x, bid = blockIdx.x;
  const int gt = bid * 256 + tid, gn = NBLK * 256;
  for (int i = gt; i < Bb * Tt * Vv; i += gn) A.xb[i] = (_Float16)A.x[i];
  for (int i = gt; i < 3 * Bb * Hh; i += gn) {
    int l = i >> 16, rem = i & 65535;
    A.ring[(l * 4 + 3) * (Bb * Hh) + rem] = (_Float16)A.h0[i];
    A.cbuf[i] = A.c0[i];
  }
  for (int i = gt; i < 3 * G4v; i += gn) {
    int l = i >> 11, c = i & 2047;
    const float* bi = (l == 0) ? A.bih0 : (l == 1) ? A.bih1 : A.bih2;
    const float* bh = (l == 0) ? A.bhh0 : (l == 1) ? A.bhh1 : A.bhh2;
    A.fbias[i] = bi[c] + bh[c];
  }
  for (int i = gt; i < Vv; i += gn) A.fbias[3 * G4v + i] = A.bfc[i];

  _Float16* img = A.wimg + bid * 32768;
  if (bid < 96) {
    int rl = bid / 32, nt = bid % 32;
    const float* Wi = (rl == 0) ? A.Wih0 : (rl == 1) ? A.Wih1 : A.Wih2;
    const int K = (rl == 0) ? Vv : Hh;
    for (int e = tid; e < 64 * K; e += 256) {
      int r = e / K, k = e - r * K;
      float v = Wi[(nt * 64 + r) * K + k];
      int idx = (rl == 0) ? (r * 104 + k) : ((r * 512 + k) ^ ((r & 7) << 3));
      img[idx] = (_Float16)v;
    }
  } else if (bid < 192) {
    int rl = (bid - 96) / 32, j0 = ((bid - 96) % 32) * 16;
    const float* Wh = (rl == 0) ? A.Whh0 : (rl == 1) ? A.Whh1 : A.Whh2;
    for (int e = tid; e < 64 * 512; e += 256) {
      int r = e >> 9, k = e & 511;
      float v = Wh[((r >> 4) * 512 + j0 + (r & 15)) * Hh + k];
      img[(r * 512 + k) ^ ((r & 7) << 3)] = (_Float16)v;
    }
  } else {
    int nt = bid - 192;
    for (int e = tid; e < 48 * 512; e += 256) {
      int r = e >> 9, k = e & 511;
      img[(r * 512 + k) ^ ((r & 7) << 3)] = (_Float16)A.Wfc[(nt * 48 + r) * Hh + k];
    }
  }
}

__global__ __launch_bounds__(NTHR) void lstm_persist(KP A) {
  __shared__ _Float16 wlds[32768];  // 64 KB, resident for all 518 steps
  const int tid = threadIdx.x, bid = blockIdx.x;
  const int lane = tid & 63, w = tid >> 6;          // 8 waves
  const int l15 = lane & 15, l4 = lane >> 4;

  int role, rl = 0, nt = 0, j0 = 0;
  if (bid < 96)       { role = 0; rl = bid / 32; nt = bid % 32; }
  else if (bid < 192) { role = 1; rl = (bid - 96) / 32; j0 = ((bid - 96) % 32) * 16; }
  else                { role = 2; nt = bid - 192; }

  {  // stage pre-swizzled weight image ONCE
    const f16x8* src = (const f16x8*)(A.wimg + bid * 32768);
    f16x8* dst = (f16x8*)wlds;
    for (int e = tid; e < 4096; e += NTHR) dst[e] = src[e];
  }

  float biasr[4] = {0.f, 0.f, 0.f, 0.f};
  float creg[4] = {0.f, 0.f, 0.f, 0.f};   // role 1: c-state lives in registers
  if (role == 0) {
#pragma unroll
    for (int n = 0; n < 4; ++n) biasr[n] = A.fbias[rl * G4v + nt * 64 + n * 16 + l15];
  } else if (role == 1) {
    const int j = j0 + l15;
#pragma unroll
    for (int q = 0; q < 4; ++q) creg[q] = A.cbuf[rl * (Bb * Hh) + (w * 16 + l4 * 4 + q) * Hh + j];
  } else {
#pragma unroll
    for (int n = 0; n < 3; ++n) biasr[n] = A.fbias[3 * G4v + nt * 48 + n * 16 + l15];
  }
  __syncthreads();

  for (int s = 0; s < NSTEP; ++s) {
    if (role == 0) {
      const int t = s - 2 * rl;
      if (t >= 0 && t < Tt) {
        f32x4 acc[4] = {};
        if (rl == 0) gemm1<6, 104, false, 4>(A.xb + t * Vv, Tt * Vv, wlds, acc);
        else         gemm1<32, 512, true, 4>(A.ring + ((rl - 1) * 4 + (t & 3)) * (Bb * Hh), Hh, wlds, acc);
        float* xgp = A.xg + (rl * 4 + (t & 3)) * (Bb * G4v) + nt * 64;
#pragma unroll
        for (int n = 0; n < 4; ++n)
#pragma unroll
          for (int q = 0; q < 4; ++q) {
            int b = w * 16 + l4 * 4 + q;
            xgp[b * G4v + n * 16 + l15] = acc[n][q] + biasr[n];
          }
      }
    } else if (role == 1) {
      const int t = s - 2 * rl - 1;
      if (t >= 0 && t < Tt) {
        f32x4 acc[4] = {};
        gemm1<32, 512, true, 4>(A.ring + (rl * 4 + ((t - 1) & 3)) * (Bb * Hh), Hh, wlds, acc);
        const float* xgp = A.xg + (rl * 4 + (t & 3)) * (Bb * G4v);
        _Float16* rp = A.ring + (rl * 4 + (t & 3)) * (Bb * Hh);
        const int j = j0 + l15;
#pragma unroll
        for (int q = 0; q < 4; ++q) {
          const int b = w * 16 + l4 * 4 + q;
          float gi = acc[0][q] + xgp[b * G4v + 0 * Hh + j];
          float gf = acc[1][q] + xgp[b * G4v + 1 * Hh + j];
          float gg = acc[2][q] + xgp[b * G4v + 2 * Hh + j];
          float go = acc[3][q] + xgp[b * G4v + 3 * Hh + j];
          float iv = sigf(gi), fv = sigf(gf), gv = tanhf(gg), ov = sigf(go);
          float cn = fv * creg[q] + iv * gv;
          creg[q] = cn;
          float hv = ov * tanhf(cn);
          rp[b * Hh + j] = (_Float16)hv;
          if (t == Tt - 1) {
            A.out[OUT_H + (rl * Bb + b) * Hh + j] = hv;
            A.out[OUT_C + (rl * Bb + b) * Hh + j] = cn;
          }
        }
      }
    } else {
      const int t = s - 6;
      if (t >= 0 && t < Tt) {
        f32x4 acc[3] = {};
        gemm1<32, 512, true, 3>(A.ring + (8 + (t & 3)) * (Bb * Hh), Hh, wlds, acc);
#pragma unroll
        for (int n = 0; n < 3; ++n)
#pragma unroll
          for (int q = 0; q < 4; ++q) {
            int b = w * 16 + l4 * 4 + q;
            A.out[(b * Tt + t) * Vv + nt * 48 + n * 16 + l15] = acc[n][q] + biasr[n];
          }
      }
    }
    gbar(A.bar, (unsigned)(s + 1));
  }
}

extern "C" void kernel_launch(void* const* d_in, const int* in_sizes, int n_in,
                              void* d_out, int out_size, void* d_ws, size_t ws_size,
                              hipStream_t stream) {
  char* base = (char*)d_ws;
  KP a;
  a.x    = (const float*)d_in[0];
  a.h0   = (const float*)d_in[1];
  a.c0   = (const float*)d_in[2];
  a.Wih0 = (const float*)d_in[3];  a.Whh0 = (const float*)d_in[4];
  a.bih0 = (const float*)d_in[5];  a.bhh0 = (const float*)d_in[6];
  a.Wih1 = (const float*)d_in[7];  a.Whh1 = (const float*)d_in[8];
  a.bih1 = (const float*)d_in[9];  a.bhh1 = (const float*)d_in[10];
  a.Wih2 = (const float*)d_in[11]; a.Whh2 = (const float*)d_in[12];
  a.bih2 = (const float*)d_in[13]; a.bhh2 = (const float*)d_in[14];
  a.Wfc  = (const float*)d_in[15]; a.bfc  = (const float*)d_in[16];
  a.out  = (float*)d_out;
  a.bar   = (unsigned*)base;                    // 2 KB
  a.fbias = (float*)(base + 2048);              // 25,600 B reserved
  a.wimg  = (_Float16*)(base + 27648);          // 12,713,984 B
  a.xg    = (float*)(base + 12741632);          // 12,582,912 B
  a.xb    = (_Float16*)(base + 25324544);       // 12,582,912 B
  a.ring  = (_Float16*)(base + 37907456);       // 1,572,864 B
  a.cbuf  = (float*)(base + 39480320);          // 786,432 B   (total ~40.3 MB)

  hipMemsetAsync(a.bar, 0, 2048, stream);
  hipLaunchKernelGGL(prologue_kernel, dim3(NBLK), dim3(256), 0, stream, a);
  hipLaunchKernelGGL(lstm_persist, dim3(NBLK), dim3(NTHR), 0, stream, a);
}

// Round 4
// 5765.702 us; speedup vs baseline: 2.9236x; 2.9236x over previous
//
#include <hip/hip_runtime.h>

#define Bb 128
#define Tt 512
#define Vv 96
#define Hh 512
#define G4v 2048
#define NBLK 194
#define NTHR 512
#define NSTEP 518
#define OUT_H 6291456
#define OUT_C 6488064

typedef _Float16 f16x4 __attribute__((ext_vector_type(4)));
typedef _Float16 f16x8 __attribute__((ext_vector_type(8)));
typedef float f32x4 __attribute__((ext_vector_type(4)));

struct KP {
  const float *x, *h0, *c0;
  const float *Wih0, *Whh0, *bih0, *bhh0;
  const float *Wih1, *Whh1, *bih1, *bhh1;
  const float *Wih2, *Whh2, *bih2, *bhh2;
  const float *Wfc, *bfc;
  float* out;
  unsigned* bar;     // [0]=gen, [32]=root, [64+g*32]=group counters (monotone)
  float* fbias;      // [3*2048 + 96]
  _Float16* wimg;    // [194][32768] per-block pre-swizzled LDS images
  float* xg;         // [3][4][Bb][G4v]
  _Float16* xb;      // [Bb][Tt][Vv]
  _Float16* ring;    // [3][4][Bb][Hh]
  float* cbuf;       // [3][Bb][Hh]
};

__device__ __forceinline__ float sigf(float x) { return 1.f / (1.f + __expf(-x)); }

// Device-coherent (MALL, sc1) relaxed accessors — no wbl2/inv cache maintenance.
__device__ __forceinline__ float ld_dc_f32(const float* p) {
  unsigned u = __hip_atomic_load((const unsigned*)p, __ATOMIC_RELAXED, __HIP_MEMORY_SCOPE_AGENT);
  return __uint_as_float(u);
}
__device__ __forceinline__ void st_dc_f32(float* p, float v) {
  __hip_atomic_store((unsigned*)p, __float_as_uint(v), __ATOMIC_RELAXED, __HIP_MEMORY_SCOPE_AGENT);
}
__device__ __forceinline__ f16x4 ld_dc_f16x4(const _Float16* p) {
  unsigned long long u = __hip_atomic_load((const unsigned long long*)p, __ATOMIC_RELAXED, __HIP_MEMORY_SCOPE_AGENT);
  union { unsigned long long u; f16x4 f; } c; c.u = u; return c.f;
}
__device__ __forceinline__ void st_dc_u32(unsigned* p, unsigned v) {
  __hip_atomic_store(p, v, __ATOMIC_RELAXED, __HIP_MEMORY_SCOPE_AGENT);
}

// Grid barrier, monotone relaxed counters. Data visibility: all shared data uses
// sc1 write-through accessors; __syncthreads drains vmcnt(0) before arrival.
__device__ __forceinline__ void gbar(unsigned* bar, unsigned target) {
  __syncthreads();   // drains vmcnt -> block's sc1 stores are at MALL
  if (threadIdx.x == 0) {
    const unsigned g = (unsigned)blockIdx.x >> 5;            // 0..6
    const unsigned gcnt = (g == 6u) ? (NBLK - 6 * 32) : 32u;
    unsigned p = __hip_atomic_fetch_add(&bar[64 + g * 32], 1u, __ATOMIC_RELAXED, __HIP_MEMORY_SCOPE_AGENT);
    if (p == target * gcnt - 1u) {
      unsigned rp = __hip_atomic_fetch_add(&bar[32], 1u, __ATOMIC_RELAXED, __HIP_MEMORY_SCOPE_AGENT);
      if (rp == target * 7u - 1u) {
        __hip_atomic_store(&bar[0], target, __ATOMIC_RELAXED, __HIP_MEMORY_SCOPE_AGENT);
      } else {
        goto spin;
      }
    } else {
    spin:
      int guard = 0;
      while (__hip_atomic_load(&bar[0], __ATOMIC_RELAXED, __HIP_MEMORY_SCOPE_AGENT) < target) {
        if (++guard > 2000000) break;   // deadlock terminates; absmax diagnoses
        __builtin_amdgcn_s_sleep(1);
      }
    }
  }
  __syncthreads();
  asm volatile("" ::: "memory");
}

// [128 x NF*16] += A[128 x K] * W^T. 8 waves split M (wave w owns rows w*16..w*16+15).
// A loads batched 8-deep for MALL latency hiding; DC=true -> sc1 coherent loads.
template <int KSTEPS, int LSTRIDE, bool SWZ, int NF, bool DC>
__device__ __forceinline__ void gemm1(const _Float16* __restrict__ Abase, int astride,
                                      const _Float16* lds, f32x4 (&acc)[NF]) {
  const int lane = threadIdx.x & 63;
  const int w = threadIdx.x >> 6;
  const int l15 = lane & 15, l4 = lane >> 4;
  const _Float16* ap = Abase + (w * 16 + l15) * astride + l4 * 4;
#pragma unroll
  for (int kb = 0; kb < (KSTEPS + 7) / 8; ++kb) {
    f16x4 av[8];
#pragma unroll
    for (int i = 0; i < 8; ++i) {
      if (kb * 8 + i < KSTEPS) {
        const _Float16* p = ap + (kb * 8 + i) * 16;
        av[i] = DC ? ld_dc_f16x4(p) : *(const f16x4*)p;
      }
    }
#pragma unroll
    for (int i = 0; i < 8; ++i) {
      if (kb * 8 + i < KSTEPS) {
        const int kk = (kb * 8 + i) * 16;
#pragma unroll
        for (int n = 0; n < NF; ++n) {
          const int r = n * 16 + l15;
          int idx = r * LSTRIDE + kk + l4 * 4;
          if (SWZ) idx ^= (r & 7) << 3;
          f16x4 bv = *(const f16x4*)(lds + idx);
          acc[n] = __builtin_amdgcn_mfma_f32_16x16x16f16(av[i], bv, acc[n], 0, 0, 0);
        }
      }
    }
  }
}

__global__ __launch_bounds__(256) void prologue_kernel(KP A) {
  const int tid = threadIdx.x, bid = blockIdx.x;
  const int gt = bid * 256 + tid, gn = NBLK * 256;
  for (int i = gt; i < Bb * Tt * Vv; i += gn) A.xb[i] = (_Float16)A.x[i];
  for (int i = gt; i < 3 * Bb * Hh; i += gn) {
    int l = i >> 16, rem = i & 65535;
    A.ring[(l * 4 + 3) * (Bb * Hh) + rem] = (_Float16)A.h0[i];
    A.cbuf[i] = A.c0[i];
  }
  for (int i = gt; i < 3 * G4v; i += gn) {
    int l = i >> 11, c = i & 2047;
    const float* bi = (l == 0) ? A.bih0 : (l == 1) ? A.bih1 : A.bih2;
    const float* bh = (l == 0) ? A.bhh0 : (l == 1) ? A.bhh1 : A.bhh2;
    A.fbias[i] = bi[c] + bh[c];
  }
  for (int i = gt; i < Vv; i += gn) A.fbias[3 * G4v + i] = A.bfc[i];

  _Float16* img = A.wimg + bid * 32768;
  if (bid < 96) {
    int rl = bid / 32, nt = bid % 32;
    const float* Wi = (rl == 0) ? A.Wih0 : (rl == 1) ? A.Wih1 : A.Wih2;
    const int K = (rl == 0) ? Vv : Hh;
    for (int e = tid; e < 64 * K; e += 256) {
      int r = e / K, k = e - r * K;
      float v = Wi[(nt * 64 + r) * K + k];
      int idx = (rl == 0) ? (r * 104 + k) : ((r * 512 + k) ^ ((r & 7) << 3));
      img[idx] = (_Float16)v;
    }
  } else if (bid < 192) {
    int rl = (bid - 96) / 32, j0 = ((bid - 96) % 32) * 16;
    const float* Wh = (rl == 0) ? A.Whh0 : (rl == 1) ? A.Whh1 : A.Whh2;
    for (int e = tid; e < 64 * 512; e += 256) {
      int r = e >> 9, k = e & 511;
      float v = Wh[((r >> 4) * 512 + j0 + (r & 15)) * Hh + k];
      img[(r * 512 + k) ^ ((r & 7) << 3)] = (_Float16)v;
    }
  } else {
    int nt = bid - 192;
    for (int e = tid; e < 48 * 512; e += 256) {
      int r = e >> 9, k = e & 511;
      img[(r * 512 + k) ^ ((r & 7) << 3)] = (_Float16)A.Wfc[(nt * 48 + r) * Hh + k];
    }
  }
}

__global__ __launch_bounds__(NTHR) void lstm_persist(KP A) {
  __shared__ _Float16 wlds[32768];  // 64 KB, resident for all 518 steps
  const int tid = threadIdx.x, bid = blockIdx.x;
  const int lane = tid & 63, w = tid >> 6;          // 8 waves
  const int l15 = lane & 15, l4 = lane >> 4;

  int role, rl = 0, nt = 0, j0 = 0;
  if (bid < 96)       { role = 0; rl = bid / 32; nt = bid % 32; }
  else if (bid < 192) { role = 1; rl = (bid - 96) / 32; j0 = ((bid - 96) % 32) * 16; }
  else                { role = 2; nt = bid - 192; }

  {  // stage pre-swizzled weight image ONCE (clean data from prologue kernel)
    const f16x8* src = (const f16x8*)(A.wimg + bid * 32768);
    f16x8* dst = (f16x8*)wlds;
    for (int e = tid; e < 4096; e += NTHR) dst[e] = src[e];
  }

  float biasr[4] = {0.f, 0.f, 0.f, 0.f};
  float creg[4] = {0.f, 0.f, 0.f, 0.f};   // role 1: c-state lives in registers
  if (role == 0) {
#pragma unroll
    for (int n = 0; n < 4; ++n) biasr[n] = A.fbias[rl * G4v + nt * 64 + n * 16 + l15];
  } else if (role == 1) {
    const int j = j0 + l15;
#pragma unroll
    for (int q = 0; q < 4; ++q) creg[q] = A.cbuf[rl * (Bb * Hh) + (w * 16 + l4 * 4 + q) * Hh + j];
  } else {
#pragma unroll
    for (int n = 0; n < 3; ++n) biasr[n] = A.fbias[3 * G4v + nt * 48 + n * 16 + l15];
  }
  __syncthreads();

  for (int s = 0; s < NSTEP; ++s) {
    if (role == 0) {
      const int t = s - 2 * rl;
      if (t >= 0 && t < Tt) {
        f32x4 acc[4] = {};
        if (rl == 0) gemm1<6, 104, false, 4, false>(A.xb + t * Vv, Tt * Vv, wlds, acc);
        else         gemm1<32, 512, true, 4, true>(A.ring + ((rl - 1) * 4 + (t & 3)) * (Bb * Hh), Hh, wlds, acc);
        float* xgp = A.xg + (rl * 4 + (t & 3)) * (Bb * G4v) + nt * 64;
#pragma unroll
        for (int n = 0; n < 4; ++n)
#pragma unroll
          for (int q = 0; q < 4; ++q) {
            int b = w * 16 + l4 * 4 + q;
            st_dc_f32(xgp + b * G4v + n * 16 + l15, acc[n][q] + biasr[n]);
          }
      }
    } else if (role == 1) {
      const int t = s - 2 * rl - 1;
      if (t >= 0 && t < Tt) {
        // issue xg loads first (independent of GEMM -> latency hidden under MFMA)
        const float* xgp = A.xg + (rl * 4 + (t & 3)) * (Bb * G4v);
        const int j = j0 + l15;
        float xr[4][4];
#pragma unroll
        for (int g2 = 0; g2 < 4; ++g2)
#pragma unroll
          for (int q = 0; q < 4; ++q) {
            int b = w * 16 + l4 * 4 + q;
            xr[g2][q] = ld_dc_f32(xgp + b * G4v + g2 * Hh + j);
          }
        f32x4 acc[4] = {};
        gemm1<32, 512, true, 4, true>(A.ring + (rl * 4 + ((t - 1) & 3)) * (Bb * Hh), Hh, wlds, acc);
        _Float16* rp = A.ring + (rl * 4 + (t & 3)) * (Bb * Hh);
#pragma unroll
        for (int q = 0; q < 4; ++q) {
          const int b = w * 16 + l4 * 4 + q;
          float gi = acc[0][q] + xr[0][q];
          float gf = acc[1][q] + xr[1][q];
          float gg = acc[2][q] + xr[2][q];
          float go = acc[3][q] + xr[3][q];
          float iv = sigf(gi), fv = sigf(gf), gv = tanhf(gg), ov = sigf(go);
          float cn = fv * creg[q] + iv * gv;
          creg[q] = cn;
          float hv = ov * tanhf(cn);
          // pack f16 pairs across adjacent lanes -> one 4B sc1 store per even lane
          union { _Float16 h; unsigned short u; } cv; cv.h = (_Float16)hv;
          unsigned hb = cv.u;
          unsigned ob = (unsigned)__shfl_xor((int)hb, 1, 64);
          if ((l15 & 1) == 0) {
            st_dc_u32((unsigned*)(rp + b * Hh + j), hb | (ob << 16));
          }
          if (t == Tt - 1) {
            A.out[OUT_H + (rl * Bb + b) * Hh + j] = hv;
            A.out[OUT_C + (rl * Bb + b) * Hh + j] = cn;
          }
        }
      }
    } else {
      const int t = s - 6;
      if (t >= 0 && t < Tt) {
        f32x4 acc[3] = {};
        gemm1<32, 512, true, 3, true>(A.ring + (8 + (t & 3)) * (Bb * Hh), Hh, wlds, acc);
#pragma unroll
        for (int n = 0; n < 3; ++n)
#pragma unroll
          for (int q = 0; q < 4; ++q) {
            int b = w * 16 + l4 * 4 + q;
            A.out[(b * Tt + t) * Vv + nt * 48 + n * 16 + l15] = acc[n][q] + biasr[n];
          }
      }
    }
    gbar(A.bar, (unsigned)(s + 1));
  }
}

extern "C" void kernel_launch(void* const* d_in, const int* in_sizes, int n_in,
                              void* d_out, int out_size, void* d_ws, size_t ws_size,
                              hipStream_t stream) {
  char* base = (char*)d_ws;
  KP a;
  a.x    = (const float*)d_in[0];
  a.h0   = (const float*)d_in[1];
  a.c0   = (const float*)d_in[2];
  a.Wih0 = (const float*)d_in[3];  a.Whh0 = (const float*)d_in[4];
  a.bih0 = (const float*)d_in[5];  a.bhh0 = (const float*)d_in[6];
  a.Wih1 = (const float*)d_in[7];  a.Whh1 = (const float*)d_in[8];
  a.bih1 = (const float*)d_in[9];  a.bhh1 = (const float*)d_in[10];
  a.Wih2 = (const float*)d_in[11]; a.Whh2 = (const float*)d_in[12];
  a.bih2 = (const float*)d_in[13]; a.bhh2 = (const float*)d_in[14];
  a.Wfc  = (const float*)d_in[15]; a.bfc  = (const float*)d_in[16];
  a.out  = (float*)d_out;
  a.bar   = (unsigned*)base;                    // 2 KB
  a.fbias = (float*)(base + 2048);              // 25,600 B reserved
  a.wimg  = (_Float16*)(base + 27648);          // 12,713,984 B
  a.xg    = (float*)(base + 12741632);          // 12,582,912 B
  a.xb    = (_Float16*)(base + 25324544);       // 12,582,912 B
  a.ring  = (_Float16*)(base + 37907456);       // 1,572,864 B
  a.cbuf  = (float*)(base + 39480320);          // 786,432 B   (total ~40.3 MB)

  hipMemsetAsync(a.bar, 0, 2048, stream);
  hipLaunchKernelGGL(prologue_kernel, dim3(NBLK), dim3(256), 0, stream, a);
  hipLaunchKernelGGL(lstm_persist, dim3(NBLK), dim3(NTHR), 0, stream, a);
}